// Round 9
// baseline (207.048 us; speedup 1.0000x reference)
//
#include <hip/hip_runtime.h>

#define H      128
#define OBSROW 141
#define GPB    16     // graphs per block (MFMA N dimension)
#define NT     256    // 4 waves; each wave owns 32 output channels (2 x 16-subtiles)

typedef __bf16 bf16x8 __attribute__((ext_vector_type(8)));
typedef float  f32x4  __attribute__((ext_vector_type(4)));

__device__ __forceinline__ float eluf(float v) {
    return v > 0.0f ? v : (__expf(v) - 1.0f);
}
__device__ __forceinline__ f32x4 mf(bf16x8 a, bf16x8 b, f32x4 c) {
    return __builtin_amdgcn_mfma_f32_16x16x32_bf16(a, b, c, 0, 0, 0);
}
// elu 4 floats -> 4 bf16, one aligned b64 store
__device__ __forceinline__ void store_pk4(unsigned short* dst, f32x4 a) {
    union { unsigned short u[4]; unsigned long long v; } pk;
    #pragma unroll
    for (int r = 0; r < 4; r++) {
        __bf16 b = (__bf16)eluf(a[r]);
        pk.u[r] = *(unsigned short*)&b;
    }
    *(unsigned long long*)dst = pk.v;
}

// ws (bf16 elems): [0)Wrel 3*16384 | [49152)Wroot 3*16384 | [98304)We_b pad[128][64] | [106496)We_j pad[128][32]
#define WS_ROOT 49152
#define WS_EB   98304
#define WS_EJ   106496
#define WS_TOT  110592

__global__ void convert_weights(const float* __restrict__ Wr, const float* __restrict__ Wo,
                                const float* __restrict__ Web, const float* __restrict__ Wej,
                                __bf16* __restrict__ ws) {
    const int i = blockIdx.x * 256 + threadIdx.x;
    if (i < WS_ROOT) {
        ws[i] = (__bf16)Wr[i];
    } else if (i < WS_EB) {
        ws[i] = (__bf16)Wo[i - WS_ROOT];
    } else if (i < WS_EJ) {
        const int j = i - WS_EB, o = j >> 6, f = j & 63;
        ws[i] = (__bf16)(f < 33 ? Web[o*33 + f] : 0.0f);
    } else if (i < WS_TOT) {
        const int j = i - WS_EJ, o = j >> 5, f = j & 31;
        ws[i] = (__bf16)(f < 9 ? Wej[o*9 + f] : 0.0f);
    }
}

// X layout: [node 13][hc 16][graph 16][hi 8] bf16; channel = hc*8+hi
// Gathered features OVERLAY the top of Xs: ushort [19456, 26624) = node 9..12 region.
// That region is also reused as the f32 decoder-partial buffer at the end.
#define G0U 19456   // joints jj at G0U+jj*512, base at G0U+6144

__launch_bounds__(NT, 2)   // 2 waves/EU -> 256-reg cap; demand ~240 -> NO spill.
                           // 2 blocks/CU resident (same as measured R6/R8 reality).
__global__ void gnn_fused(const float* __restrict__ obs,
                          const float* __restrict__ be_b, const float* __restrict__ be_j,
                          const float* __restrict__ b_rel,
                          const float* __restrict__ W_dec, const float* __restrict__ b_dec,
                          const __bf16* __restrict__ wsb,
                          float* __restrict__ out, int B)
{
    __shared__ __align__(16) unsigned short Xs[13*2048];   // 53248 B total

    const int tid  = threadIdx.x;
    const int wave = tid >> 6;     // 0..3 -> channels [wave*32, wave*32+32)
    const int lane = tid & 63;
    const int q    = lane >> 4;    // k-quarter (inputs) / channel-quad (output)
    const int c    = lane & 15;    // graph (B-side) == weight output-row offset (A-side)
    const int g0   = blockIdx.x * GPB;

    static constexpr int ODEG[13]    = {4,2,2,1,2,2,1,2,2,1,2,2,1};
    static constexpr int ODST[13][4] = {
        {1,4,7,10},{0,2,0,0},{1,3,0,0},{2,0,0,0},{0,5,0,0},{4,6,0,0},{5,0,0,0},
        {0,8,0,0},{7,9,0,0},{8,0,0,0},{0,11,0,0},{10,12,0,0},{11,0,0,0}};

    // swapped-operand output: lane (q,c) holds graph c, channels o = wave*32+s*16+q*4+r
    const int hcs0 = wave*4 + (q>>1);          // hc for s=0 (s adds 2)
    const int wofs = c*8 + (q&1)*4;            // graph*8 + hi base (ushort units)
    // weight row base for subtile s: (wave*32 + s*16 + c)*128 + q*8
    const int rb0 = (wave*32 + c)*128 + q*8;
    const int rb1 = (wave*32 + 16 + c)*128 + q*8;

    // ---------------- stage 0: coalesced obs copy global -> LDS raw (bytes [0,9024)) ----
    {
        float* raw = (float*)Xs;
        for (int i = tid; i < GPB*OBSROW; i += NT) {
            const int g = i / OBSROW;
            raw[i] = ((g0 + g) < B) ? obs[(g0+g)*OBSROW + (i - g*OBSROW)] : 0.0f;
        }
    }
    // ---- prefetch layer-0 weight frags; latency hidden under stage-0/1 barriers ----
    bf16x8 Wt[2][4], Wr[2][4];
    #pragma unroll
    for (int ks = 0; ks < 4; ks++) {
        Wt[0][ks] = *(const bf16x8*)(wsb + WS_ROOT + rb0 + ks*32);
        Wt[1][ks] = *(const bf16x8*)(wsb + WS_ROOT + rb1 + ks*32);
        Wr[0][ks] = *(const bf16x8*)(wsb + rb0 + ks*32);
        Wr[1][ks] = *(const bf16x8*)(wsb + rb1 + ks*32);
    }
    __syncthreads();

    // ---------------- stage 1: gather + cvt raw -> gathered (top of Xs) ----------------
    {
        const float* raw = (const float*)Xs;
        for (int s = tid; s < 6144; s += NT) {
            const int jj = s >> 9, rem = s & 511;
            const int fc = rem >> 7, g = (rem >> 3) & 15, hi = rem & 7;
            const int f = fc*8 + hi;
            float v = 0.0f;
            if (f < 9)
                v = raw[g*OBSROW + (f/3)*47 + 9 + (f%3)*12 + jj];
            *(__bf16*)&Xs[G0U + s] = (__bf16)v;
        }
        for (int s = tid; s < 1024; s += NT) {
            const int fc = s >> 7, rem = s & 127, g = rem >> 3, hi = rem & 7;
            const int f = fc*8 + hi;
            float v = 0.0f;
            if (f < 33) {
                const int tt = f / 11, i2 = f % 11;
                v = raw[g*OBSROW + tt*47 + (i2 < 9 ? i2 : 36 + i2)];
            }
            *(__bf16*)&Xs[G0U + 6144 + s] = (__bf16)v;
        }
    }
    __syncthreads();

    // ---------------- encoders (A = weights, B = features) ----------------
    // Nodes 0..8 outputs (ushort [0,18432)) don't overlap gathered ([19456,26624)) -> direct.
    // Nodes 9..12 outputs overlap gathered -> accumulate in regs, store after barrier.
    {
        const int orow = wave*32 + c;
        // node 0 (base), K=64 padded
        const bf16x8 a0 = *(const bf16x8*)&Xs[G0U + 6144 + q*128 + c*8];
        const bf16x8 a1 = *(const bf16x8*)&Xs[G0U + 6144 + 512 + q*128 + c*8];
        #pragma unroll
        for (int s = 0; s < 2; s++) {
            const bf16x8 u0 = *(const bf16x8*)(wsb + WS_EB + (orow + s*16)*64 + q*8);
            const bf16x8 u1 = *(const bf16x8*)(wsb + WS_EB + (orow + s*16)*64 + 32 + q*8);
            const float4 b4 = *(const float4*)&be_b[wave*32 + s*16 + q*4];
            f32x4 acc = {b4.x, b4.y, b4.z, b4.w};
            acc = mf(u0, a0, acc);
            acc = mf(u1, a1, acc);
            store_pk4(&Xs[(hcs0 + s*2)*128 + wofs], acc);
        }
        // joints 0..11, K=32; hoist the two weight frags and biases
        bf16x8 uj[2];
        f32x4 bias[2];
        #pragma unroll
        for (int s = 0; s < 2; s++) {
            uj[s] = *(const bf16x8*)(wsb + WS_EJ + (orow + s*16)*32 + q*8);
            const float4 b4 = *(const float4*)&be_j[wave*32 + s*16 + q*4];
            bias[s] = (f32x4){b4.x, b4.y, b4.z, b4.w};
        }
        f32x4 dacc[2][4];   // deferred: nodes 9..12
        #pragma unroll
        for (int jj = 0; jj < 12; jj++) {
            const bf16x8 a = *(const bf16x8*)&Xs[G0U + jj*512 + q*128 + c*8];
            #pragma unroll
            for (int s = 0; s < 2; s++) {
                f32x4 acc = bias[s];
                acc = mf(uj[s], a, acc);
                if (jj < 8)
                    store_pk4(&Xs[(1+jj)*2048 + (hcs0 + s*2)*128 + wofs], acc);
                else
                    dacc[s][jj-8] = acc;
            }
        }
        __syncthreads();   // all gathered-feature reads complete
        #pragma unroll
        for (int t = 0; t < 4; t++) {
            store_pk4(&Xs[(9+t)*2048 +  hcs0     *128 + wofs], dacc[0][t]);
            store_pk4(&Xs[(9+t)*2048 + (hcs0+2)  *128 + wofs], dacc[1][t]);
        }
    }
    __syncthreads();

    // ---------------- GraphConv layers 0,1 (fused root+rel, full unroll) ----------------
    // B-frag (X) for (n,ks): Xs + n*2048 + ks*512 + q*128 + c*8 (wave-contiguous 1KB)
    const unsigned short* xb_base = Xs + q*128 + c*8;
    #pragma unroll 1
    for (int l = 0; l < 2; l++) {
        f32x4 acc[13][2];
        #pragma unroll
        for (int s = 0; s < 2; s++) {
            const float4 b4 = *(const float4*)&b_rel[l*H + wave*32 + s*16 + q*4];
            const f32x4 bias = {b4.x, b4.y, b4.z, b4.w};
            #pragma unroll
            for (int n = 0; n < 13; n++) acc[n][s] = bias;
        }
        #pragma unroll
        for (int h = 0; h < 2; h++) {
            const unsigned short* xh = xb_base + 2*h*512;
            #pragma unroll
            for (int n = 0; n < 13; n++) {
                const bf16x8 xa0 = *(const bf16x8*)(xh + n*2048);
                const bf16x8 xa1 = *(const bf16x8*)(xh + n*2048 + 512);
                acc[n][0] = mf(Wt[0][2*h  ], xa0, acc[n][0]);
                acc[n][0] = mf(Wt[0][2*h+1], xa1, acc[n][0]);
                acc[n][1] = mf(Wt[1][2*h  ], xa0, acc[n][1]);
                acc[n][1] = mf(Wt[1][2*h+1], xa1, acc[n][1]);
                #pragma unroll
                for (int e = 0; e < 4; e++) {
                    if (e < ODEG[n]) {
                        const int d = ODST[n][e];
                        acc[d][0] = mf(Wr[0][2*h  ], xa0, acc[d][0]);
                        acc[d][0] = mf(Wr[0][2*h+1], xa1, acc[d][0]);
                        acc[d][1] = mf(Wr[1][2*h  ], xa0, acc[d][1]);
                        acc[d][1] = mf(Wr[1][2*h+1], xa1, acc[d][1]);
                    }
                }
            }
        }
        __syncthreads();   // A: all X reads done
        #pragma unroll
        for (int n = 0; n < 13; n++) {
            store_pk4(&Xs[n*2048 +  hcs0     *128 + wofs], acc[n][0]);
            store_pk4(&Xs[n*2048 + (hcs0 + 2)*128 + wofs], acc[n][1]);
        }
        // prefetch next layer's weights; drain is hidden under barrier B's wait
        #pragma unroll
        for (int ks = 0; ks < 4; ks++) {
            Wt[0][ks] = *(const bf16x8*)(wsb + WS_ROOT + (l+1)*16384 + rb0 + ks*32);
            Wt[1][ks] = *(const bf16x8*)(wsb + WS_ROOT + (l+1)*16384 + rb1 + ks*32);
            Wr[0][ks] = *(const bf16x8*)(wsb + (l+1)*16384 + rb0 + ks*32);
            Wr[1][ks] = *(const bf16x8*)(wsb + (l+1)*16384 + rb1 + ks*32);
        }
        __syncthreads();   // B: new X visible
    }

    // ---------------- layer 2 + fused decoder (no X2 stores at all) ----------------
    {
        f32x4 acc[13][2];
        #pragma unroll
        for (int s = 0; s < 2; s++) {
            const float4 b4 = *(const float4*)&b_rel[2*H + wave*32 + s*16 + q*4];
            const f32x4 bias = {b4.x, b4.y, b4.z, b4.w};
            #pragma unroll
            for (int n = 0; n < 13; n++) acc[n][s] = bias;
        }
        #pragma unroll
        for (int h = 0; h < 2; h++) {
            const unsigned short* xh = xb_base + 2*h*512;
            #pragma unroll
            for (int n = 0; n < 13; n++) {
                const bf16x8 xa0 = *(const bf16x8*)(xh + n*2048);
                const bf16x8 xa1 = *(const bf16x8*)(xh + n*2048 + 512);
                if (n != 0) {   // node-0 output dead in last layer
                    acc[n][0] = mf(Wt[0][2*h  ], xa0, acc[n][0]);
                    acc[n][0] = mf(Wt[0][2*h+1], xa1, acc[n][0]);
                    acc[n][1] = mf(Wt[1][2*h  ], xa0, acc[n][1]);
                    acc[n][1] = mf(Wt[1][2*h+1], xa1, acc[n][1]);
                }
                #pragma unroll
                for (int e = 0; e < 4; e++) {
                    if (e < ODEG[n]) {
                        const int d = ODST[n][e];
                        if (d == 0) continue;          // dead output
                        acc[d][0] = mf(Wr[0][2*h  ], xa0, acc[d][0]);
                        acc[d][0] = mf(Wr[0][2*h+1], xa1, acc[d][0]);
                        acc[d][1] = mf(Wr[1][2*h  ], xa0, acc[d][1]);
                        acc[d][1] = mf(Wr[1][2*h+1], xa1, acc[d][1]);
                    }
                }
            }
        }
        __syncthreads();   // all layer-2 X reads done (overlay region now free)

        // decoder on f32 accumulators: p[j] = sum_ch elu(x2[j+1][ch]) * W_dec[ch]
        float wd[2][4];
        #pragma unroll
        for (int s = 0; s < 2; s++) {
            const float4 w4 = *(const float4*)&W_dec[wave*32 + s*16 + q*4];
            wd[s][0] = w4.x; wd[s][1] = w4.y; wd[s][2] = w4.z; wd[s][3] = w4.w;
        }
        float* part = (float*)&Xs[G0U];   // [4 waves][12 joints][16 graphs] f32 = 3 KB
        float p[12];
        #pragma unroll
        for (int j = 0; j < 12; j++) {
            float pp = 0.0f;
            #pragma unroll
            for (int s = 0; s < 2; s++)
                #pragma unroll
                for (int r = 0; r < 4; r++)
                    pp += eluf(acc[j+1][s][r]) * wd[s][r];
            pp += __shfl_xor(pp, 16);   // sum over q (channel quads)
            pp += __shfl_xor(pp, 32);
            p[j] = pp;
        }
        if (q == 0) {
            #pragma unroll
            for (int j = 0; j < 12; j++)
                part[wave*192 + j*16 + c] = p[j];
        }
        __syncthreads();
        if (tid < 192) {   // t = c2*12 + j2 -> coalesced out stores
            const int c2 = tid / 12, j2 = tid - c2*12;
            const float ssum = part[      j2*16 + c2] + part[192 + j2*16 + c2]
                             + part[384 + j2*16 + c2] + part[576 + j2*16 + c2];
            if ((g0 + c2) < B)
                out[(g0 + c2)*12 + j2] = ssum + b_dec[0];
        }
    }
}

extern "C" void kernel_launch(void* const* d_in, const int* in_sizes, int n_in,
                              void* d_out, int out_size, void* d_ws, size_t ws_size,
                              hipStream_t stream) {
    const float* obs   = (const float*)d_in[0];
    const float* We_b  = (const float*)d_in[1];
    const float* be_b  = (const float*)d_in[2];
    const float* We_j  = (const float*)d_in[3];
    const float* be_j  = (const float*)d_in[4];
    const float* W_rel = (const float*)d_in[5];
    const float* W_root= (const float*)d_in[6];
    const float* b_rel = (const float*)d_in[7];
    const float* W_dec = (const float*)d_in[8];
    const float* b_dec = (const float*)d_in[9];
    float* out = (float*)d_out;
    __bf16* wsb = (__bf16*)d_ws;

    const int B = in_sizes[0] / OBSROW;
    convert_weights<<<(WS_TOT + 255) / 256, 256, 0, stream>>>(W_rel, W_root, We_b, We_j, wsb);
    const int blocks = (B + GPB - 1) / GPB;
    gnn_fused<<<blocks, NT, 0, stream>>>(obs, be_b, be_j, b_rel, W_dec, b_dec,
                                         wsb, out, B);
}

// Round 10
// 194.294 us; speedup vs baseline: 1.0656x; 1.0656x over previous
//
#include <hip/hip_runtime.h>

#define H      128
#define OBSROW 141
#define GPB    16     // graphs per block (MFMA N dimension)
#define NT     512    // 8 waves; each wave owns 16 output channels (one 16x16 o-subtile)

typedef __bf16 bf16x8 __attribute__((ext_vector_type(8)));
typedef float  f32x4  __attribute__((ext_vector_type(4)));

__device__ __forceinline__ float eluf(float v) {
    return v > 0.0f ? v : (__expf(v) - 1.0f);
}
__device__ __forceinline__ f32x4 mf(bf16x8 a, bf16x8 b, f32x4 c) {
    return __builtin_amdgcn_mfma_f32_16x16x32_bf16(a, b, c, 0, 0, 0);
}
// elu 4 floats -> 4 bf16, one aligned b64 store
__device__ __forceinline__ void store_pk4(unsigned short* dst, f32x4 a) {
    union { unsigned short u[4]; unsigned long long v; } pk;
    #pragma unroll
    for (int r = 0; r < 4; r++) {
        __bf16 b = (__bf16)eluf(a[r]);
        pk.u[r] = *(unsigned short*)&b;
    }
    *(unsigned long long*)dst = pk.v;
}

// ws (bf16 elems): [0)Wrel 3*16384 | [49152)Wroot 3*16384 | [98304)We_b pad[128][64] | [106496)We_j pad[128][32]
#define WS_ROOT 49152
#define WS_EB   98304
#define WS_EJ   106496
#define WS_TOT  110592

__global__ void convert_weights(const float* __restrict__ Wr, const float* __restrict__ Wo,
                                const float* __restrict__ Web, const float* __restrict__ Wej,
                                __bf16* __restrict__ ws) {
    const int i = blockIdx.x * 256 + threadIdx.x;
    if (i < WS_ROOT) {
        ws[i] = (__bf16)Wr[i];
    } else if (i < WS_EB) {
        ws[i] = (__bf16)Wo[i - WS_ROOT];
    } else if (i < WS_EJ) {
        const int j = i - WS_EB, o = j >> 6, f = j & 63;
        ws[i] = (__bf16)(f < 33 ? Web[o*33 + f] : 0.0f);
    } else if (i < WS_TOT) {
        const int j = i - WS_EJ, o = j >> 5, f = j & 31;
        ws[i] = (__bf16)(f < 9 ? Wej[o*9 + f] : 0.0f);
    }
}

// X layout: [node 13][hc 16][graph 16][hi 8] bf16; channel = hc*8+hi
// Gathered features OVERLAY the top of Xs: ushort [19456, 26624) = node 9.5..13 region.
// Encoder outputs for nodes 9..12 are computed into registers, stored after a barrier.
// The same region is reused as the f32 decoder-partial buffer at the end.
#define G0U 19456   // joints jj at G0U+jj*512, base at G0U+6144

__launch_bounds__(NT, 4)   // 4 waves/EU -> 128-reg cap; 16ch body measured ~104 unified
                           // (R2: 52 VGPR + 52 AGPR, WRITE=1.5MB) -> no spill.
                           // 2 blocks/CU (reg-limited) = 16 waves/CU.
__global__ void gnn_fused(const float* __restrict__ obs,
                          const float* __restrict__ be_b, const float* __restrict__ be_j,
                          const float* __restrict__ b_rel,
                          const float* __restrict__ W_dec, const float* __restrict__ b_dec,
                          const __bf16* __restrict__ wsb,
                          float* __restrict__ out, int B)
{
    __shared__ __align__(16) unsigned short Xs[13*2048];   // 53248 B total

    const int tid  = threadIdx.x;
    const int wave = tid >> 6;     // 0..7 -> channels [wave*16, wave*16+16)
    const int lane = tid & 63;
    const int q    = lane >> 4;    // k-quarter (inputs) / channel-quad (output)
    const int c    = lane & 15;    // graph (B-side) == weight output-row offset (A-side)
    const int g0   = blockIdx.x * GPB;

    static constexpr int ODEG[13]    = {4,2,2,1,2,2,1,2,2,1,2,2,1};
    static constexpr int ODST[13][4] = {
        {1,4,7,10},{0,2,0,0},{1,3,0,0},{2,0,0,0},{0,5,0,0},{4,6,0,0},{5,0,0,0},
        {0,8,0,0},{7,9,0,0},{8,0,0,0},{0,11,0,0},{10,12,0,0},{11,0,0,0}};

    // swapped-operand output: lane (q,c) holds graph c, channels o = wave*16 + q*4 + r
    const int hcd  = wave*2 + (q>>1);          // destination hc
    const int wofs = c*8 + (q&1)*4;            // graph*8 + hi base (ushort units)

    // ---------------- stage 0: coalesced obs copy global -> LDS raw (bytes [0,9024)) ----
    {
        float* raw = (float*)Xs;
        for (int i = tid; i < GPB*OBSROW; i += NT) {
            const int g = i / OBSROW;
            raw[i] = ((g0 + g) < B) ? obs[(g0+g)*OBSROW + (i - g*OBSROW)] : 0.0f;
        }
    }
    __syncthreads();

    // ---------------- stage 1: gather + cvt raw -> gathered (top of Xs) ----------------
    {
        const float* raw = (const float*)Xs;
        for (int s = tid; s < 6144; s += NT) {
            const int jj = s >> 9, rem = s & 511;
            const int fc = rem >> 7, g = (rem >> 3) & 15, hi = rem & 7;
            const int f = fc*8 + hi;
            float v = 0.0f;
            if (f < 9)
                v = raw[g*OBSROW + (f/3)*47 + 9 + (f%3)*12 + jj];
            *(__bf16*)&Xs[G0U + s] = (__bf16)v;
        }
        for (int s = tid; s < 1024; s += NT) {
            const int fc = s >> 7, rem = s & 127, g = rem >> 3, hi = rem & 7;
            const int f = fc*8 + hi;
            float v = 0.0f;
            if (f < 33) {
                const int tt = f / 11, i2 = f % 11;
                v = raw[g*OBSROW + tt*47 + (i2 < 9 ? i2 : 36 + i2)];
            }
            *(__bf16*)&Xs[G0U + 6144 + s] = (__bf16)v;
        }
    }
    __syncthreads();

    // ---------------- encoders (A = weights, B = features) ----------------
    // Nodes 0..8 outputs (ushort [0,18432)) don't overlap gathered ([19456,26624)) -> direct.
    // Nodes 9..12 outputs overlap gathered -> accumulate in regs, store after barrier.
    {
        const int orow = wave*16 + c;
        // node 0 (base), K=64 padded -> 2 MFMAs, direct store
        {
            const bf16x8 u0 = *(const bf16x8*)(wsb + WS_EB + orow*64 + q*8);
            const bf16x8 u1 = *(const bf16x8*)(wsb + WS_EB + orow*64 + 32 + q*8);
            const bf16x8 a0 = *(const bf16x8*)&Xs[G0U + 6144 + q*128 + c*8];
            const bf16x8 a1 = *(const bf16x8*)&Xs[G0U + 6144 + 512 + q*128 + c*8];
            const float4 b4 = *(const float4*)&be_b[wave*16 + q*4];
            f32x4 acc = {b4.x, b4.y, b4.z, b4.w};
            acc = mf(u0, a0, acc);
            acc = mf(u1, a1, acc);
            store_pk4(&Xs[hcd*128 + wofs], acc);
        }
        // joints 0..11, K=32 -> 1 MFMA each; nodes 9..12 deferred
        {
            const bf16x8 uj = *(const bf16x8*)(wsb + WS_EJ + orow*32 + q*8);
            const float4 b4 = *(const float4*)&be_j[wave*16 + q*4];
            const f32x4 bias = {b4.x, b4.y, b4.z, b4.w};
            f32x4 dacc[4];
            #pragma unroll
            for (int jj = 0; jj < 12; jj++) {
                const bf16x8 a = *(const bf16x8*)&Xs[G0U + jj*512 + q*128 + c*8];
                f32x4 acc = bias;
                acc = mf(uj, a, acc);
                if (jj < 8)
                    store_pk4(&Xs[(1+jj)*2048 + hcd*128 + wofs], acc);
                else
                    dacc[jj-8] = acc;
            }
            __syncthreads();   // all gathered-feature reads complete
            #pragma unroll
            for (int t = 0; t < 4; t++)
                store_pk4(&Xs[(9+t)*2048 + hcd*128 + wofs], dacc[t]);
        }
    }
    __syncthreads();

    // ---------------- GraphConv layers 0,1 (fused root+rel, full-direct MFMA) --------
    // B-frag (X) for (n,ks): Xs + n*2048 + ks*512 + q*128 + c*8 (wave-contiguous 1KB)
    // A-frag (W) for ks:     w + (wave*16+c)*128 + ks*32 + q*8
    // Each x-frag pair read ONCE; feeds root (own acc) and rel (direct into dst acc).
    const unsigned short* xr = Xs + q*128 + c*8;
    #pragma unroll 1
    for (int l = 0; l < 2; l++) {
        const __bf16* wr = wsb + l*16384 + (wave*16 + c)*128 + q*8;
        const __bf16* wo = wsb + WS_ROOT + l*16384 + (wave*16 + c)*128 + q*8;
        const float4 b4 = *(const float4*)&b_rel[l*H + wave*16 + q*4];
        const f32x4 bias = {b4.x, b4.y, b4.z, b4.w};

        f32x4 acc[13];
        #pragma unroll
        for (int n = 0; n < 13; n++) acc[n] = bias;

        #pragma unroll 1
        for (int h = 0; h < 2; h++) {
            const bf16x8 br0 = *(const bf16x8*)(wr + h*64);
            const bf16x8 br1 = *(const bf16x8*)(wr + h*64 + 32);
            const bf16x8 bo0 = *(const bf16x8*)(wo + h*64);
            const bf16x8 bo1 = *(const bf16x8*)(wo + h*64 + 32);
            const unsigned short* xh = xr + h*1024;
            #pragma unroll
            for (int n = 0; n < 13; n++) {
                const bf16x8 xa0 = *(const bf16x8*)(xh + n*2048);
                const bf16x8 xa1 = *(const bf16x8*)(xh + n*2048 + 512);
                acc[n] = mf(bo0, xa0, acc[n]);
                acc[n] = mf(bo1, xa1, acc[n]);
                #pragma unroll
                for (int e = 0; e < 4; e++) {
                    if (e < ODEG[n]) {
                        const int d = ODST[n][e];
                        acc[d] = mf(br0, xa0, acc[d]);
                        acc[d] = mf(br1, xa1, acc[d]);
                    }
                }
            }
        }
        __syncthreads();   // A: all X reads done
        #pragma unroll
        for (int n = 0; n < 13; n++)
            store_pk4(&Xs[n*2048 + hcd*128 + wofs], acc[n]);
        __syncthreads();   // B: new X visible
    }

    // ---------------- layer 2 + fused decoder (no X2 stores) ----------------
    {
        const __bf16* wr = wsb + 2*16384 + (wave*16 + c)*128 + q*8;
        const __bf16* wo = wsb + WS_ROOT + 2*16384 + (wave*16 + c)*128 + q*8;
        const float4 b4 = *(const float4*)&b_rel[2*H + wave*16 + q*4];
        const f32x4 bias = {b4.x, b4.y, b4.z, b4.w};

        f32x4 acc[13];
        #pragma unroll
        for (int n = 0; n < 13; n++) acc[n] = bias;

        #pragma unroll 1
        for (int h = 0; h < 2; h++) {
            const bf16x8 br0 = *(const bf16x8*)(wr + h*64);
            const bf16x8 br1 = *(const bf16x8*)(wr + h*64 + 32);
            const bf16x8 bo0 = *(const bf16x8*)(wo + h*64);
            const bf16x8 bo1 = *(const bf16x8*)(wo + h*64 + 32);
            const unsigned short* xh = xr + h*1024;
            #pragma unroll
            for (int n = 0; n < 13; n++) {
                const bf16x8 xa0 = *(const bf16x8*)(xh + n*2048);
                const bf16x8 xa1 = *(const bf16x8*)(xh + n*2048 + 512);
                if (n != 0) {                          // node-0 output dead in last layer
                    acc[n] = mf(bo0, xa0, acc[n]);
                    acc[n] = mf(bo1, xa1, acc[n]);
                }
                #pragma unroll
                for (int e = 0; e < 4; e++) {
                    if (e < ODEG[n]) {
                        const int d = ODST[n][e];
                        if (d == 0) continue;          // dead output
                        acc[d] = mf(br0, xa0, acc[d]);
                        acc[d] = mf(br1, xa1, acc[d]);
                    }
                }
            }
        }
        __syncthreads();   // all layer-2 X reads done (overlay region now free)

        // decoder on f32 accumulators: p[j] = sum_ch elu(x2[j+1][ch]) * W_dec[ch]
        float wd[4];
        {
            const float4 w4 = *(const float4*)&W_dec[wave*16 + q*4];
            wd[0] = w4.x; wd[1] = w4.y; wd[2] = w4.z; wd[3] = w4.w;
        }
        float* part = (float*)&Xs[G0U];   // [8 waves][12 joints][16 graphs] f32 = 6 KB
        #pragma unroll
        for (int j = 0; j < 12; j++) {
            float pp = 0.0f;
            #pragma unroll
            for (int r = 0; r < 4; r++)
                pp += eluf(acc[j+1][r]) * wd[r];
            pp += __shfl_xor(pp, 16);   // sum over q (channel quads)
            pp += __shfl_xor(pp, 32);
            if (q == 0)
                part[wave*192 + j*16 + c] = pp;
        }
        __syncthreads();
        if (tid < 192) {   // t = c2*12 + j2 -> coalesced out stores
            const int c2 = tid / 12, j2 = tid - c2*12;
            float ssum = 0.0f;
            #pragma unroll
            for (int w = 0; w < 8; w++)
                ssum += part[w*192 + j2*16 + c2];
            if ((g0 + c2) < B)
                out[(g0 + c2)*12 + j2] = ssum + b_dec[0];
        }
    }
}

extern "C" void kernel_launch(void* const* d_in, const int* in_sizes, int n_in,
                              void* d_out, int out_size, void* d_ws, size_t ws_size,
                              hipStream_t stream) {
    const float* obs   = (const float*)d_in[0];
    const float* We_b  = (const float*)d_in[1];
    const float* be_b  = (const float*)d_in[2];
    const float* We_j  = (const float*)d_in[3];
    const float* be_j  = (const float*)d_in[4];
    const float* W_rel = (const float*)d_in[5];
    const float* W_root= (const float*)d_in[6];
    const float* b_rel = (const float*)d_in[7];
    const float* W_dec = (const float*)d_in[8];
    const float* b_dec = (const float*)d_in[9];
    float* out = (float*)d_out;
    __bf16* wsb = (__bf16*)d_ws;

    const int B = in_sizes[0] / OBSROW;
    convert_weights<<<(WS_TOT + 255) / 256, 256, 0, stream>>>(W_rel, W_root, We_b, We_j, wsb);
    const int blocks = (B + GPB - 1) / GPB;
    gnn_fused<<<blocks, NT, 0, stream>>>(obs, be_b, be_j, b_rel, W_dec, b_dec,
                                         wsb, out, B);
}

// Round 11
// 194.277 us; speedup vs baseline: 1.0657x; 1.0001x over previous
//
#include <hip/hip_runtime.h>

#define H      128
#define OBSROW 141
#define GPB    16     // graphs per block (MFMA N dimension)
#define NT     512    // 8 waves; each wave owns 16 output channels (one 16x16 o-subtile)

typedef __bf16 bf16x8 __attribute__((ext_vector_type(8)));
typedef float  f32x4  __attribute__((ext_vector_type(4)));

__device__ __forceinline__ float eluf(float v) {
    return v > 0.0f ? v : (__expf(v) - 1.0f);
}
__device__ __forceinline__ f32x4 mf(bf16x8 a, bf16x8 b, f32x4 c) {
    return __builtin_amdgcn_mfma_f32_16x16x32_bf16(a, b, c, 0, 0, 0);
}
// elu 4 floats -> 4 bf16, one aligned b64 store
__device__ __forceinline__ void store_pk4(unsigned short* dst, f32x4 a) {
    union { unsigned short u[4]; unsigned long long v; } pk;
    #pragma unroll
    for (int r = 0; r < 4; r++) {
        __bf16 b = (__bf16)eluf(a[r]);
        pk.u[r] = *(unsigned short*)&b;
    }
    *(unsigned long long*)dst = pk.v;
}

// ws (bf16 elems): [0)Wrel 3*16384 | [49152)Wroot 3*16384 | [98304)We_b pad[128][64] | [106496)We_j pad[128][32]
#define WS_ROOT 49152
#define WS_EB   98304
#define WS_EJ   106496
#define WS_TOT  110592

__global__ void convert_weights(const float* __restrict__ Wr, const float* __restrict__ Wo,
                                const float* __restrict__ Web, const float* __restrict__ Wej,
                                __bf16* __restrict__ ws) {
    const int i = blockIdx.x * 256 + threadIdx.x;
    if (i < WS_ROOT) {
        ws[i] = (__bf16)Wr[i];
    } else if (i < WS_EB) {
        ws[i] = (__bf16)Wo[i - WS_ROOT];
    } else if (i < WS_EJ) {
        const int j = i - WS_EB, o = j >> 6, f = j & 63;
        ws[i] = (__bf16)(f < 33 ? Web[o*33 + f] : 0.0f);
    } else if (i < WS_TOT) {
        const int j = i - WS_EJ, o = j >> 5, f = j & 31;
        ws[i] = (__bf16)(f < 9 ? Wej[o*9 + f] : 0.0f);
    }
}

// X layout: [node 13][hc 16][graph 16][hi 8] bf16; channel = hc*8+hi
// Gathered features OVERLAY the top of Xs: ushort [19456, 26624) = node 9..12 region.
// Encoder outputs for nodes 9..12 are computed into registers, stored after a barrier.
// The same region is reused as the f32 decoder-partial buffer at the end.
#define G0U 19456   // joints jj at G0U+jj*512, base at G0U+6144

__launch_bounds__(NT, 4)   // 4 waves/EU -> 128-reg cap; hybrid 16ch body ~104 unified
                           // (R2-anchored: 52 VGPR + 52 AGPR) -> no spill.
                           // 2 blocks/CU = 16 waves/CU (proven R10 chassis).
__global__ void gnn_fused(const float* __restrict__ obs,
                          const float* __restrict__ be_b, const float* __restrict__ be_j,
                          const float* __restrict__ b_rel,
                          const float* __restrict__ W_dec, const float* __restrict__ b_dec,
                          const __bf16* __restrict__ wsb,
                          float* __restrict__ out, int B)
{
    __shared__ __align__(16) unsigned short Xs[13*2048];   // 53248 B total

    const int tid  = threadIdx.x;
    const int wave = tid >> 6;     // 0..7 -> channels [wave*16, wave*16+16)
    const int lane = tid & 63;
    const int q    = lane >> 4;    // k-quarter (inputs) / channel-quad (output)
    const int c    = lane & 15;    // graph (B-side) == weight output-row offset (A-side)
    const int g0   = blockIdx.x * GPB;

    static constexpr int ODEG[13]    = {4,2,2,1,2,2,1,2,2,1,2,2,1};
    static constexpr int ODST[13][4] = {
        {1,4,7,10},{0,2,0,0},{1,3,0,0},{2,0,0,0},{0,5,0,0},{4,6,0,0},{5,0,0,0},
        {0,8,0,0},{7,9,0,0},{8,0,0,0},{0,11,0,0},{10,12,0,0},{11,0,0,0}};

    // swapped-operand output: lane (q,c) holds graph c, channels o = wave*16 + q*4 + r
    const int hcd  = wave*2 + (q>>1);          // destination hc
    const int wofs = c*8 + (q&1)*4;            // graph*8 + hi base (ushort units)

    // ---------------- stage 0: coalesced obs copy global -> LDS raw (bytes [0,9024)) ----
    {
        float* raw = (float*)Xs;
        for (int i = tid; i < GPB*OBSROW; i += NT) {
            const int g = i / OBSROW;
            raw[i] = ((g0 + g) < B) ? obs[(g0+g)*OBSROW + (i - g*OBSROW)] : 0.0f;
        }
    }
    __syncthreads();

    // ---------------- stage 1: gather + cvt raw -> gathered (top of Xs) ----------------
    {
        const float* raw = (const float*)Xs;
        for (int s = tid; s < 6144; s += NT) {
            const int jj = s >> 9, rem = s & 511;
            const int fc = rem >> 7, g = (rem >> 3) & 15, hi = rem & 7;
            const int f = fc*8 + hi;
            float v = 0.0f;
            if (f < 9)
                v = raw[g*OBSROW + (f/3)*47 + 9 + (f%3)*12 + jj];
            *(__bf16*)&Xs[G0U + s] = (__bf16)v;
        }
        for (int s = tid; s < 1024; s += NT) {
            const int fc = s >> 7, rem = s & 127, g = rem >> 3, hi = rem & 7;
            const int f = fc*8 + hi;
            float v = 0.0f;
            if (f < 33) {
                const int tt = f / 11, i2 = f % 11;
                v = raw[g*OBSROW + tt*47 + (i2 < 9 ? i2 : 36 + i2)];
            }
            *(__bf16*)&Xs[G0U + 6144 + s] = (__bf16)v;
        }
    }
    __syncthreads();

    // ---------------- encoders (A = weights, B = features) ----------------
    // Nodes 0..8 outputs (ushort [0,18432)) don't overlap gathered ([19456,26624)) -> direct.
    // Nodes 9..12 outputs overlap gathered -> accumulate in regs, store after barrier.
    {
        const int orow = wave*16 + c;
        // node 0 (base), K=64 padded -> 2 MFMAs, direct store
        {
            const bf16x8 u0 = *(const bf16x8*)(wsb + WS_EB + orow*64 + q*8);
            const bf16x8 u1 = *(const bf16x8*)(wsb + WS_EB + orow*64 + 32 + q*8);
            const bf16x8 a0 = *(const bf16x8*)&Xs[G0U + 6144 + q*128 + c*8];
            const bf16x8 a1 = *(const bf16x8*)&Xs[G0U + 6144 + 512 + q*128 + c*8];
            const float4 b4 = *(const float4*)&be_b[wave*16 + q*4];
            f32x4 acc = {b4.x, b4.y, b4.z, b4.w};
            acc = mf(u0, a0, acc);
            acc = mf(u1, a1, acc);
            store_pk4(&Xs[hcd*128 + wofs], acc);
        }
        // joints 0..11, K=32 -> 1 MFMA each; nodes 9..12 deferred
        {
            const bf16x8 uj = *(const bf16x8*)(wsb + WS_EJ + orow*32 + q*8);
            const float4 b4 = *(const float4*)&be_j[wave*16 + q*4];
            const f32x4 bias = {b4.x, b4.y, b4.z, b4.w};
            f32x4 dacc[4];
            #pragma unroll
            for (int jj = 0; jj < 12; jj++) {
                const bf16x8 a = *(const bf16x8*)&Xs[G0U + jj*512 + q*128 + c*8];
                f32x4 acc = bias;
                acc = mf(uj, a, acc);
                if (jj < 8)
                    store_pk4(&Xs[(1+jj)*2048 + hcd*128 + wofs], acc);
                else
                    dacc[jj-8] = acc;
            }
            __syncthreads();   // all gathered-feature reads complete
            #pragma unroll
            for (int t = 0; t < 4; t++)
                store_pk4(&Xs[(9+t)*2048 + hcd*128 + wofs], dacc[t]);
        }
    }
    __syncthreads();

    // ---------------- GraphConv layers 0,1 (fused, HYBRID rel) ----------------
    // B-frag (X) for (n,ks): Xs + n*2048 + ks*512 + q*128 + c*8 (wave-contiguous 1KB)
    // A-frag (W) for ks:     w + (wave*16+c)*128 + ks*32 + q*8
    // Each x-frag pair read ONCE. rel: deg-1 sources -> direct MFMA into dst acc;
    // deg>=2 sources -> y-transient (2 MFMAs) + f32x4 adds. 104 MFMA/wave-layer.
    const unsigned short* xr = Xs + q*128 + c*8;
    #pragma unroll 1
    for (int l = 0; l < 2; l++) {
        const __bf16* wr = wsb + l*16384 + (wave*16 + c)*128 + q*8;
        const __bf16* wo = wsb + WS_ROOT + l*16384 + (wave*16 + c)*128 + q*8;
        const float4 b4 = *(const float4*)&b_rel[l*H + wave*16 + q*4];
        const f32x4 bias = {b4.x, b4.y, b4.z, b4.w};

        f32x4 acc[13];
        #pragma unroll
        for (int n = 0; n < 13; n++) acc[n] = bias;

        #pragma unroll 1
        for (int h = 0; h < 2; h++) {
            const bf16x8 br0 = *(const bf16x8*)(wr + h*64);
            const bf16x8 br1 = *(const bf16x8*)(wr + h*64 + 32);
            const bf16x8 bo0 = *(const bf16x8*)(wo + h*64);
            const bf16x8 bo1 = *(const bf16x8*)(wo + h*64 + 32);
            const unsigned short* xh = xr + h*1024;
            #pragma unroll
            for (int n = 0; n < 13; n++) {
                const bf16x8 xa0 = *(const bf16x8*)(xh + n*2048);
                const bf16x8 xa1 = *(const bf16x8*)(xh + n*2048 + 512);
                acc[n] = mf(bo0, xa0, acc[n]);
                acc[n] = mf(bo1, xa1, acc[n]);
                if (ODEG[n] == 1) {
                    const int d = ODST[n][0];
                    acc[d] = mf(br0, xa0, acc[d]);
                    acc[d] = mf(br1, xa1, acc[d]);
                } else {
                    f32x4 y = {0.f,0.f,0.f,0.f};
                    y = mf(br0, xa0, y);
                    y = mf(br1, xa1, y);
                    #pragma unroll
                    for (int e = 0; e < 4; e++)
                        if (e < ODEG[n]) acc[ODST[n][e]] += y;
                }
            }
        }
        __syncthreads();   // A: all X reads done
        #pragma unroll
        for (int n = 0; n < 13; n++)
            store_pk4(&Xs[n*2048 + hcd*128 + wofs], acc[n]);
        __syncthreads();   // B: new X visible
    }

    // ---------------- layer 2 + fused decoder (no X2 stores) ----------------
    {
        const __bf16* wr = wsb + 2*16384 + (wave*16 + c)*128 + q*8;
        const __bf16* wo = wsb + WS_ROOT + 2*16384 + (wave*16 + c)*128 + q*8;
        const float4 b4 = *(const float4*)&b_rel[2*H + wave*16 + q*4];
        const f32x4 bias = {b4.x, b4.y, b4.z, b4.w};

        f32x4 acc[13];
        #pragma unroll
        for (int n = 0; n < 13; n++) acc[n] = bias;

        #pragma unroll 1
        for (int h = 0; h < 2; h++) {
            const bf16x8 br0 = *(const bf16x8*)(wr + h*64);
            const bf16x8 br1 = *(const bf16x8*)(wr + h*64 + 32);
            const bf16x8 bo0 = *(const bf16x8*)(wo + h*64);
            const bf16x8 bo1 = *(const bf16x8*)(wo + h*64 + 32);
            const unsigned short* xh = xr + h*1024;
            #pragma unroll
            for (int n = 0; n < 13; n++) {
                const bf16x8 xa0 = *(const bf16x8*)(xh + n*2048);
                const bf16x8 xa1 = *(const bf16x8*)(xh + n*2048 + 512);
                if (n != 0) {                          // node-0 output dead in last layer
                    acc[n] = mf(bo0, xa0, acc[n]);
                    acc[n] = mf(bo1, xa1, acc[n]);
                }
                if (ODEG[n] == 1) {
                    const int d = ODST[n][0];          // deg-1 dsts are never node 0
                    acc[d] = mf(br0, xa0, acc[d]);
                    acc[d] = mf(br1, xa1, acc[d]);
                } else {
                    f32x4 y = {0.f,0.f,0.f,0.f};
                    y = mf(br0, xa0, y);
                    y = mf(br1, xa1, y);
                    #pragma unroll
                    for (int e = 0; e < 4; e++)
                        if (e < ODEG[n]) {
                            const int d = ODST[n][e];
                            if (d != 0) acc[d] += y;   // dead output
                        }
                }
            }
        }
        __syncthreads();   // all layer-2 X reads done (overlay region now free)

        // decoder on f32 accumulators: p[j] = sum_ch elu(x2[j+1][ch]) * W_dec[ch]
        float wd[4];
        {
            const float4 w4 = *(const float4*)&W_dec[wave*16 + q*4];
            wd[0] = w4.x; wd[1] = w4.y; wd[2] = w4.z; wd[3] = w4.w;
        }
        float* part = (float*)&Xs[G0U];   // [8 waves][12 joints][16 graphs] f32 = 6 KB
        #pragma unroll
        for (int j = 0; j < 12; j++) {
            float pp = 0.0f;
            #pragma unroll
            for (int r = 0; r < 4; r++)
                pp += eluf(acc[j+1][r]) * wd[r];
            pp += __shfl_xor(pp, 16);   // sum over q (channel quads)
            pp += __shfl_xor(pp, 32);
            if (q == 0)
                part[wave*192 + j*16 + c] = pp;
        }
        __syncthreads();
        if (tid < 192) {   // t = c2*12 + j2 -> coalesced out stores
            const int c2 = tid / 12, j2 = tid - c2*12;
            float ssum = 0.0f;
            #pragma unroll
            for (int w = 0; w < 8; w++)
                ssum += part[w*192 + j2*16 + c2];
            if ((g0 + c2) < B)
                out[(g0 + c2)*12 + j2] = ssum + b_dec[0];
        }
    }
}

extern "C" void kernel_launch(void* const* d_in, const int* in_sizes, int n_in,
                              void* d_out, int out_size, void* d_ws, size_t ws_size,
                              hipStream_t stream) {
    const float* obs   = (const float*)d_in[0];
    const float* We_b  = (const float*)d_in[1];
    const float* be_b  = (const float*)d_in[2];
    const float* We_j  = (const float*)d_in[3];
    const float* be_j  = (const float*)d_in[4];
    const float* W_rel = (const float*)d_in[5];
    const float* W_root= (const float*)d_in[6];
    const float* b_rel = (const float*)d_in[7];
    const float* W_dec = (const float*)d_in[8];
    const float* b_dec = (const float*)d_in[9];
    float* out = (float*)d_out;
    __bf16* wsb = (__bf16*)d_ws;

    const int B = in_sizes[0] / OBSROW;
    convert_weights<<<(WS_TOT + 255) / 256, 256, 0, stream>>>(W_rel, W_root, We_b, We_j, wsb);
    const int blocks = (B + GPB - 1) / GPB;
    gnn_fused<<<blocks, NT, 0, stream>>>(obs, be_b, be_j, b_rel, W_dec, b_dec,
                                         wsb, out, B);
}

// Round 12
// 193.156 us; speedup vs baseline: 1.0719x; 1.0058x over previous
//
#include <hip/hip_runtime.h>

#define H      128
#define OBSROW 141
#define GPB    16     // graphs per block (MFMA N dimension)
#define NT     512    // 8 waves; each wave owns 16 output channels (one 16x16 o-subtile)

typedef __bf16 bf16x8 __attribute__((ext_vector_type(8)));
typedef float  f32x4  __attribute__((ext_vector_type(4)));

__device__ __forceinline__ float eluf(float v) {
    return v > 0.0f ? v : (__expf(v) - 1.0f);
}
__device__ __forceinline__ f32x4 mf(bf16x8 a, bf16x8 b, f32x4 c) {
    return __builtin_amdgcn_mfma_f32_16x16x32_bf16(a, b, c, 0, 0, 0);
}
// elu 4 floats -> 4 bf16, one aligned b64 store
__device__ __forceinline__ void store_pk4(unsigned short* dst, f32x4 a) {
    union { unsigned short u[4]; unsigned long long v; } pk;
    #pragma unroll
    for (int r = 0; r < 4; r++) {
        __bf16 b = (__bf16)eluf(a[r]);
        pk.u[r] = *(unsigned short*)&b;
    }
    *(unsigned long long*)dst = pk.v;
}

// ws (bf16 elems): [0)Wrel 3*16384 | [49152)Wroot 3*16384 | [98304)We_b pad[128][64] | [106496)We_j pad[128][32]
#define WS_ROOT 49152
#define WS_EB   98304
#define WS_EJ   106496
#define WS_TOT  110592

__global__ void convert_weights(const float* __restrict__ Wr, const float* __restrict__ Wo,
                                const float* __restrict__ Web, const float* __restrict__ Wej,
                                __bf16* __restrict__ ws) {
    const int i = blockIdx.x * 256 + threadIdx.x;
    if (i < WS_ROOT) {
        ws[i] = (__bf16)Wr[i];
    } else if (i < WS_EB) {
        ws[i] = (__bf16)Wo[i - WS_ROOT];
    } else if (i < WS_EJ) {
        const int j = i - WS_EB, o = j >> 6, f = j & 63;
        ws[i] = (__bf16)(f < 33 ? Web[o*33 + f] : 0.0f);
    } else if (i < WS_TOT) {
        const int j = i - WS_EJ, o = j >> 5, f = j & 31;
        ws[i] = (__bf16)(f < 9 ? Wej[o*9 + f] : 0.0f);
    }
}

// X layout: [node 13][hc 16][graph 16][hi 8] bf16; channel = hc*8+hi
// Gathered features OVERLAY the top of Xs: ushort [19456, 26624) = node 9..12 region.
// Encoder outputs for nodes 9..12 are computed into registers, stored after a barrier.
// The same region is reused as the f32 decoder-partial buffer at the end.
#define G0U 19456   // joints jj at G0U+jj*512, base at G0U+6144

__launch_bounds__(NT, 4)   // 4 waves/EU -> 128-reg cap; R10 measured ~100 unified,
                           // +16 for hoisted weight frags -> ~116, no spill.
                           // 2 blocks/CU = 16 waves/CU (proven R10 chassis).
__global__ void gnn_fused(const float* __restrict__ obs,
                          const float* __restrict__ be_b, const float* __restrict__ be_j,
                          const float* __restrict__ b_rel,
                          const float* __restrict__ W_dec, const float* __restrict__ b_dec,
                          const __bf16* __restrict__ wsb,
                          float* __restrict__ out, int B)
{
    __shared__ __align__(16) unsigned short Xs[13*2048];   // 53248 B total

    const int tid  = threadIdx.x;
    const int wave = tid >> 6;     // 0..7 -> channels [wave*16, wave*16+16)
    const int lane = tid & 63;
    const int q    = lane >> 4;    // k-quarter (inputs) / channel-quad (output)
    const int c    = lane & 15;    // graph (B-side) == weight output-row offset (A-side)
    const int g0   = blockIdx.x * GPB;

    static constexpr int ODEG[13]    = {4,2,2,1,2,2,1,2,2,1,2,2,1};
    static constexpr int ODST[13][4] = {
        {1,4,7,10},{0,2,0,0},{1,3,0,0},{2,0,0,0},{0,5,0,0},{4,6,0,0},{5,0,0,0},
        {0,8,0,0},{7,9,0,0},{8,0,0,0},{0,11,0,0},{10,12,0,0},{11,0,0,0}};

    // swapped-operand output: lane (q,c) holds graph c, channels o = wave*16 + q*4 + r
    const int hcd  = wave*2 + (q>>1);          // destination hc
    const int wofs = c*8 + (q&1)*4;            // graph*8 + hi base (ushort units)
    const int wrow = (wave*16 + c)*128 + q*8;  // weight A-frag row base

    // ---------------- stage 0: coalesced obs copy global -> LDS raw (bytes [0,9024)) ----
    {
        float* raw = (float*)Xs;
        for (int i = tid; i < GPB*OBSROW; i += NT) {
            const int g = i / OBSROW;
            raw[i] = ((g0 + g) < B) ? obs[(g0+g)*OBSROW + (i - g*OBSROW)] : 0.0f;
        }
    }
    __syncthreads();

    // ---------------- stage 1: gather + cvt raw -> gathered (top of Xs) ----------------
    {
        const float* raw = (const float*)Xs;
        for (int s = tid; s < 6144; s += NT) {
            const int jj = s >> 9, rem = s & 511;
            const int fc = rem >> 7, g = (rem >> 3) & 15, hi = rem & 7;
            const int f = fc*8 + hi;
            float v = 0.0f;
            if (f < 9)
                v = raw[g*OBSROW + (f/3)*47 + 9 + (f%3)*12 + jj];
            *(__bf16*)&Xs[G0U + s] = (__bf16)v;
        }
        for (int s = tid; s < 1024; s += NT) {
            const int fc = s >> 7, rem = s & 127, g = rem >> 3, hi = rem & 7;
            const int f = fc*8 + hi;
            float v = 0.0f;
            if (f < 33) {
                const int tt = f / 11, i2 = f % 11;
                v = raw[g*OBSROW + tt*47 + (i2 < 9 ? i2 : 36 + i2)];
            }
            *(__bf16*)&Xs[G0U + 6144 + s] = (__bf16)v;
        }
    }
    __syncthreads();

    // ---- prefetch layer-0 weight frags; latency hidden under encoder MFMAs ----
    bf16x8 wfr[4], wfo[4];
    #pragma unroll
    for (int ks = 0; ks < 4; ks++) {
        wfr[ks] = *(const bf16x8*)(wsb + wrow + ks*32);
        wfo[ks] = *(const bf16x8*)(wsb + WS_ROOT + wrow + ks*32);
    }

    // ---------------- encoders (A = weights, B = features) ----------------
    // Nodes 0..8 outputs (ushort [0,18432)) don't overlap gathered ([19456,26624)) -> direct.
    // Nodes 9..12 outputs overlap gathered -> accumulate in regs, store after barrier.
    {
        const int orow = wave*16 + c;
        // node 0 (base), K=64 padded -> 2 MFMAs, direct store
        {
            const bf16x8 u0 = *(const bf16x8*)(wsb + WS_EB + orow*64 + q*8);
            const bf16x8 u1 = *(const bf16x8*)(wsb + WS_EB + orow*64 + 32 + q*8);
            const bf16x8 a0 = *(const bf16x8*)&Xs[G0U + 6144 + q*128 + c*8];
            const bf16x8 a1 = *(const bf16x8*)&Xs[G0U + 6144 + 512 + q*128 + c*8];
            const float4 b4 = *(const float4*)&be_b[wave*16 + q*4];
            f32x4 acc = {b4.x, b4.y, b4.z, b4.w};
            acc = mf(u0, a0, acc);
            acc = mf(u1, a1, acc);
            store_pk4(&Xs[hcd*128 + wofs], acc);
        }
        // joints 0..11, K=32 -> 1 MFMA each; nodes 9..12 deferred
        {
            const bf16x8 uj = *(const bf16x8*)(wsb + WS_EJ + orow*32 + q*8);
            const float4 b4 = *(const float4*)&be_j[wave*16 + q*4];
            const f32x4 bias = {b4.x, b4.y, b4.z, b4.w};
            f32x4 dacc[4];
            #pragma unroll
            for (int jj = 0; jj < 12; jj++) {
                const bf16x8 a = *(const bf16x8*)&Xs[G0U + jj*512 + q*128 + c*8];
                f32x4 acc = bias;
                acc = mf(uj, a, acc);
                if (jj < 8)
                    store_pk4(&Xs[(1+jj)*2048 + hcd*128 + wofs], acc);
                else
                    dacc[jj-8] = acc;
            }
            __syncthreads();   // all gathered-feature reads complete
            #pragma unroll
            for (int t = 0; t < 4; t++)
                store_pk4(&Xs[(9+t)*2048 + hcd*128 + wofs], dacc[t]);
        }
    }
    __syncthreads();

    // ---------------- GraphConv layers 0,1 (fused, all-direct rel, h unrolled) --------
    // B-frag (X) for (n,ks): Xs + n*2048 + ks*512 + q*128 + c*8 (wave-contiguous 1KB)
    // All 8 weight frags live for the layer; h fully unrolled so the scheduler can
    // front-load all 52 ds_read_b128 and overlap them with the MFMA stream.
    const unsigned short* xr = Xs + q*128 + c*8;
    #pragma unroll 1
    for (int l = 0; l < 2; l++) {
        const float4 b4 = *(const float4*)&b_rel[l*H + wave*16 + q*4];
        const f32x4 bias = {b4.x, b4.y, b4.z, b4.w};

        f32x4 acc[13];
        #pragma unroll
        for (int n = 0; n < 13; n++) acc[n] = bias;

        #pragma unroll
        for (int h = 0; h < 2; h++) {
            const unsigned short* xh = xr + h*1024;
            #pragma unroll
            for (int n = 0; n < 13; n++) {
                const bf16x8 xa0 = *(const bf16x8*)(xh + n*2048);
                const bf16x8 xa1 = *(const bf16x8*)(xh + n*2048 + 512);
                acc[n] = mf(wfo[2*h  ], xa0, acc[n]);
                acc[n] = mf(wfo[2*h+1], xa1, acc[n]);
                #pragma unroll
                for (int e = 0; e < 4; e++) {
                    if (e < ODEG[n]) {
                        const int d = ODST[n][e];
                        acc[d] = mf(wfr[2*h  ], xa0, acc[d]);
                        acc[d] = mf(wfr[2*h+1], xa1, acc[d]);
                    }
                }
            }
        }
        __syncthreads();   // A: all X reads done
        #pragma unroll
        for (int n = 0; n < 13; n++)
            store_pk4(&Xs[n*2048 + hcd*128 + wofs], acc[n]);
        // prefetch next layer's weight frags; drain hides under barrier B
        #pragma unroll
        for (int ks = 0; ks < 4; ks++) {
            wfr[ks] = *(const bf16x8*)(wsb + (l+1)*16384 + wrow + ks*32);
            wfo[ks] = *(const bf16x8*)(wsb + WS_ROOT + (l+1)*16384 + wrow + ks*32);
        }
        __syncthreads();   // B: new X visible
    }

    // ---------------- layer 2 + fused decoder (weights already prefetched) ----------
    {
        const float4 b4 = *(const float4*)&b_rel[2*H + wave*16 + q*4];
        const f32x4 bias = {b4.x, b4.y, b4.z, b4.w};

        f32x4 acc[13];
        #pragma unroll
        for (int n = 0; n < 13; n++) acc[n] = bias;

        #pragma unroll
        for (int h = 0; h < 2; h++) {
            const unsigned short* xh = xr + h*1024;
            #pragma unroll
            for (int n = 0; n < 13; n++) {
                const bf16x8 xa0 = *(const bf16x8*)(xh + n*2048);
                const bf16x8 xa1 = *(const bf16x8*)(xh + n*2048 + 512);
                if (n != 0) {                          // node-0 output dead in last layer
                    acc[n] = mf(wfo[2*h  ], xa0, acc[n]);
                    acc[n] = mf(wfo[2*h+1], xa1, acc[n]);
                }
                #pragma unroll
                for (int e = 0; e < 4; e++) {
                    if (e < ODEG[n]) {
                        const int d = ODST[n][e];
                        if (d == 0) continue;          // dead output
                        acc[d] = mf(wfr[2*h  ], xa0, acc[d]);
                        acc[d] = mf(wfr[2*h+1], xa1, acc[d]);
                    }
                }
            }
        }
        __syncthreads();   // all layer-2 X reads done (overlay region now free)

        // decoder on f32 accumulators: p[j] = sum_ch elu(x2[j+1][ch]) * W_dec[ch]
        float wd[4];
        {
            const float4 w4 = *(const float4*)&W_dec[wave*16 + q*4];
            wd[0] = w4.x; wd[1] = w4.y; wd[2] = w4.z; wd[3] = w4.w;
        }
        float* part = (float*)&Xs[G0U];   // [8 waves][12 joints][16 graphs] f32 = 6 KB
        #pragma unroll
        for (int j = 0; j < 12; j++) {
            float pp = 0.0f;
            #pragma unroll
            for (int r = 0; r < 4; r++)
                pp += eluf(acc[j+1][r]) * wd[r];
            pp += __shfl_xor(pp, 16);   // sum over q (channel quads)
            pp += __shfl_xor(pp, 32);
            if (q == 0)
                part[wave*192 + j*16 + c] = pp;
        }
        __syncthreads();
        if (tid < 192) {   // t = c2*12 + j2 -> coalesced out stores
            const int c2 = tid / 12, j2 = tid - c2*12;
            float ssum = 0.0f;
            #pragma unroll
            for (int w = 0; w < 8; w++)
                ssum += part[w*192 + j2*16 + c2];
            if ((g0 + c2) < B)
                out[(g0 + c2)*12 + j2] = ssum + b_dec[0];
        }
    }
}

extern "C" void kernel_launch(void* const* d_in, const int* in_sizes, int n_in,
                              void* d_out, int out_size, void* d_ws, size_t ws_size,
                              hipStream_t stream) {
    const float* obs   = (const float*)d_in[0];
    const float* We_b  = (const float*)d_in[1];
    const float* be_b  = (const float*)d_in[2];
    const float* We_j  = (const float*)d_in[3];
    const float* be_j  = (const float*)d_in[4];
    const float* W_rel = (const float*)d_in[5];
    const float* W_root= (const float*)d_in[6];
    const float* b_rel = (const float*)d_in[7];
    const float* W_dec = (const float*)d_in[8];
    const float* b_dec = (const float*)d_in[9];
    float* out = (float*)d_out;
    __bf16* wsb = (__bf16*)d_ws;

    const int B = in_sizes[0] / OBSROW;
    convert_weights<<<(WS_TOT + 255) / 256, 256, 0, stream>>>(W_rel, W_root, We_b, We_j, wsb);
    const int blocks = (B + GPB - 1) / GPB;
    gnn_fused<<<blocks, NT, 0, stream>>>(obs, be_b, be_j, b_rel, W_dec, b_dec,
                                         wsb, out, B);
}

// Round 13
// 192.307 us; speedup vs baseline: 1.0767x; 1.0044x over previous
//
#include <hip/hip_runtime.h>

#define H      128
#define OBSROW 141
#define GPB    16     // graphs per block (MFMA N dimension)
#define NT     512    // 8 waves; each wave owns 16 output channels (one 16x16 o-subtile)

typedef __bf16 bf16x8 __attribute__((ext_vector_type(8)));
typedef float  f32x4  __attribute__((ext_vector_type(4)));

__device__ __forceinline__ float eluf(float v) {
    return v > 0.0f ? v : (__expf(v) - 1.0f);
}
__device__ __forceinline__ f32x4 mf(bf16x8 a, bf16x8 b, f32x4 c) {
    return __builtin_amdgcn_mfma_f32_16x16x32_bf16(a, b, c, 0, 0, 0);
}
// elu 4 floats -> 4 bf16, one aligned b64 store
__device__ __forceinline__ void store_pk4(unsigned short* dst, f32x4 a) {
    union { unsigned short u[4]; unsigned long long v; } pk;
    #pragma unroll
    for (int r = 0; r < 4; r++) {
        __bf16 b = (__bf16)eluf(a[r]);
        pk.u[r] = *(unsigned short*)&b;
    }
    *(unsigned long long*)dst = pk.v;
}

// ws (bf16 elems): [0)Wrel 3*16384 | [49152)Wroot 3*16384 | [98304)We_b pad[128][64] | [106496)We_j pad[128][32]
#define WS_ROOT 49152
#define WS_EB   98304
#define WS_EJ   106496
#define WS_TOT  110592

__global__ void convert_weights(const float* __restrict__ Wr, const float* __restrict__ Wo,
                                const float* __restrict__ Web, const float* __restrict__ Wej,
                                __bf16* __restrict__ ws) {
    const int i = blockIdx.x * 256 + threadIdx.x;
    if (i < WS_ROOT) {
        ws[i] = (__bf16)Wr[i];
    } else if (i < WS_EB) {
        ws[i] = (__bf16)Wo[i - WS_ROOT];
    } else if (i < WS_EJ) {
        const int j = i - WS_EB, o = j >> 6, f = j & 63;
        ws[i] = (__bf16)(f < 33 ? Web[o*33 + f] : 0.0f);
    } else if (i < WS_TOT) {
        const int j = i - WS_EJ, o = j >> 5, f = j & 31;
        ws[i] = (__bf16)(f < 9 ? Wej[o*9 + f] : 0.0f);
    }
}

// X layout: [node 13][hc 16][graph 16][hi 8] bf16; channel = hc*8+hi
// Fs: separate gathered-feature buffer (no overlay; 2 blocks/CU is reg-limited, so
// the extra 14 KB LDS is free). Reused as the f32 decoder-partial buffer at the end.

__launch_bounds__(NT, 4)   // 4 waves/EU -> 128-reg cap; R10 body ~100 unified -> no
                           // spill. 2 blocks/CU (reg-limited; LDS 67584*2 <= 163840).
__global__ void gnn_fused(const float* __restrict__ obs,
                          const float* __restrict__ be_b, const float* __restrict__ be_j,
                          const float* __restrict__ b_rel,
                          const float* __restrict__ W_dec, const float* __restrict__ b_dec,
                          const __bf16* __restrict__ wsb,
                          float* __restrict__ out, int B)
{
    __shared__ __align__(16) unsigned short Xs[13*2048];   // 53248 B node features
    __shared__ __align__(16) unsigned short Fs[7168];      // 14336 B gathered feats / partials

    const int tid  = threadIdx.x;
    const int wave = tid >> 6;     // 0..7 -> channels [wave*16, wave*16+16)
    const int lane = tid & 63;
    const int q    = lane >> 4;    // k-quarter (inputs) / channel-quad (output)
    const int c    = lane & 15;    // graph (B-side) == weight output-row offset (A-side)
    const int g0   = blockIdx.x * GPB;

    static constexpr int ODEG[13]    = {4,2,2,1,2,2,1,2,2,1,2,2,1};
    static constexpr int ODST[13][4] = {
        {1,4,7,10},{0,2,0,0},{1,3,0,0},{2,0,0,0},{0,5,0,0},{4,6,0,0},{5,0,0,0},
        {0,8,0,0},{7,9,0,0},{8,0,0,0},{0,11,0,0},{10,12,0,0},{11,0,0,0}};

    // swapped-operand output: lane (q,c) holds graph c, channels o = wave*16 + q*4 + r
    const int hcd  = wave*2 + (q>>1);          // destination hc
    const int wofs = c*8 + (q&1)*4;            // graph*8 + hi base (ushort units)

    // ---------- fused gather: global obs -> Fs (bf16), no raw staging, no extra barrier ----
    // Per-block obs footprint is 16*564 B = 9 KB -> L1-resident after first touch;
    // every obs column is consumed, so HBM traffic is unchanged vs a coalesced copy.
    {
        // joints at Fs[jj*512 + fc*128 + g*8 + hi] (f = fc*8+hi, f<9 valid)
        for (int s = tid; s < 6144; s += NT) {
            const int jj = s >> 9, rem = s & 511;
            const int fc = rem >> 7, g = (rem >> 3) & 15, hi = rem & 7;
            const int f = fc*8 + hi;
            float v = 0.0f;
            if (f < 9 && (g0 + g) < B)
                v = obs[(g0+g)*OBSROW + (f/3)*47 + 9 + (f%3)*12 + jj];
            *(__bf16*)&Fs[s] = (__bf16)v;
        }
        // base at Fs[6144 + fc*128 + g*8 + hi] (f = fc*8+hi, f<33 valid, K padded to 64)
        for (int s = tid; s < 1024; s += NT) {
            const int fc = s >> 7, rem = s & 127, g = rem >> 3, hi = rem & 7;
            const int f = fc*8 + hi;
            float v = 0.0f;
            if (f < 33 && (g0 + g) < B) {
                const int tt = f / 11, i2 = f % 11;   // BASE_IDX[i] = i<9 ? i : 36+i
                v = obs[(g0+g)*OBSROW + tt*47 + (i2 < 9 ? i2 : 36 + i2)];
            }
            *(__bf16*)&Fs[6144 + s] = (__bf16)v;
        }
    }
    __syncthreads();

    // ---------------- encoders (A = weights, B = features) — all 13 nodes direct ------
    {
        const int orow = wave*16 + c;
        // node 0 (base), K=64 padded -> 2 MFMAs
        {
            const bf16x8 u0 = *(const bf16x8*)(wsb + WS_EB + orow*64 + q*8);
            const bf16x8 u1 = *(const bf16x8*)(wsb + WS_EB + orow*64 + 32 + q*8);
            const bf16x8 a0 = *(const bf16x8*)&Fs[6144 + q*128 + c*8];
            const bf16x8 a1 = *(const bf16x8*)&Fs[6144 + 512 + q*128 + c*8];
            const float4 b4 = *(const float4*)&be_b[wave*16 + q*4];
            f32x4 acc = {b4.x, b4.y, b4.z, b4.w};
            acc = mf(u0, a0, acc);
            acc = mf(u1, a1, acc);
            store_pk4(&Xs[hcd*128 + wofs], acc);
        }
        // joints 0..11, K=32 -> 1 MFMA each, all direct stores
        {
            const bf16x8 uj = *(const bf16x8*)(wsb + WS_EJ + orow*32 + q*8);
            const float4 b4 = *(const float4*)&be_j[wave*16 + q*4];
            const f32x4 bias = {b4.x, b4.y, b4.z, b4.w};
            #pragma unroll
            for (int jj = 0; jj < 12; jj++) {
                const bf16x8 a = *(const bf16x8*)&Fs[jj*512 + q*128 + c*8];
                f32x4 acc = bias;
                acc = mf(uj, a, acc);
                store_pk4(&Xs[(1+jj)*2048 + hcd*128 + wofs], acc);
            }
        }
    }
    __syncthreads();

    // ---------------- GraphConv layers 0,1 (R10 champion body, verbatim) ----------------
    // B-frag (X) for (n,ks): Xs + n*2048 + ks*512 + q*128 + c*8 (wave-contiguous 1KB)
    // A-frag (W) for ks:     w + (wave*16+c)*128 + ks*32 + q*8
    // Each x-frag pair read ONCE; feeds root (own acc) and rel (direct into dst acc).
    const unsigned short* xr = Xs + q*128 + c*8;
    #pragma unroll 1
    for (int l = 0; l < 2; l++) {
        const __bf16* wr = wsb + l*16384 + (wave*16 + c)*128 + q*8;
        const __bf16* wo = wsb + WS_ROOT + l*16384 + (wave*16 + c)*128 + q*8;
        const float4 b4 = *(const float4*)&b_rel[l*H + wave*16 + q*4];
        const f32x4 bias = {b4.x, b4.y, b4.z, b4.w};

        f32x4 acc[13];
        #pragma unroll
        for (int n = 0; n < 13; n++) acc[n] = bias;

        #pragma unroll 1
        for (int h = 0; h < 2; h++) {
            const bf16x8 br0 = *(const bf16x8*)(wr + h*64);
            const bf16x8 br1 = *(const bf16x8*)(wr + h*64 + 32);
            const bf16x8 bo0 = *(const bf16x8*)(wo + h*64);
            const bf16x8 bo1 = *(const bf16x8*)(wo + h*64 + 32);
            const unsigned short* xh = xr + h*1024;
            #pragma unroll
            for (int n = 0; n < 13; n++) {
                const bf16x8 xa0 = *(const bf16x8*)(xh + n*2048);
                const bf16x8 xa1 = *(const bf16x8*)(xh + n*2048 + 512);
                acc[n] = mf(bo0, xa0, acc[n]);
                acc[n] = mf(bo1, xa1, acc[n]);
                #pragma unroll
                for (int e = 0; e < 4; e++) {
                    if (e < ODEG[n]) {
                        const int d = ODST[n][e];
                        acc[d] = mf(br0, xa0, acc[d]);
                        acc[d] = mf(br1, xa1, acc[d]);
                    }
                }
            }
        }
        __syncthreads();   // A: all X reads done
        #pragma unroll
        for (int n = 0; n < 13; n++)
            store_pk4(&Xs[n*2048 + hcd*128 + wofs], acc[n]);
        __syncthreads();   // B: new X visible
    }

    // ---------------- layer 2 + fused decoder (no X2 stores, no trailing X barrier) ----
    {
        const __bf16* wr = wsb + 2*16384 + (wave*16 + c)*128 + q*8;
        const __bf16* wo = wsb + WS_ROOT + 2*16384 + (wave*16 + c)*128 + q*8;
        const float4 b4 = *(const float4*)&b_rel[2*H + wave*16 + q*4];
        const f32x4 bias = {b4.x, b4.y, b4.z, b4.w};

        f32x4 acc[13];
        #pragma unroll
        for (int n = 0; n < 13; n++) acc[n] = bias;

        #pragma unroll 1
        for (int h = 0; h < 2; h++) {
            const bf16x8 br0 = *(const bf16x8*)(wr + h*64);
            const bf16x8 br1 = *(const bf16x8*)(wr + h*64 + 32);
            const bf16x8 bo0 = *(const bf16x8*)(wo + h*64);
            const bf16x8 bo1 = *(const bf16x8*)(wo + h*64 + 32);
            const unsigned short* xh = xr + h*1024;
            #pragma unroll
            for (int n = 0; n < 13; n++) {
                const bf16x8 xa0 = *(const bf16x8*)(xh + n*2048);
                const bf16x8 xa1 = *(const bf16x8*)(xh + n*2048 + 512);
                if (n != 0) {                          // node-0 output dead in last layer
                    acc[n] = mf(bo0, xa0, acc[n]);
                    acc[n] = mf(bo1, xa1, acc[n]);
                }
                #pragma unroll
                for (int e = 0; e < 4; e++) {
                    if (e < ODEG[n]) {
                        const int d = ODST[n][e];
                        if (d == 0) continue;          // dead output
                        acc[d] = mf(br0, xa0, acc[d]);
                        acc[d] = mf(br1, xa1, acc[d]);
                    }
                }
            }
        }
        // No barrier needed: decoder uses only this wave's registers + Fs (idle since
        // the encoder barrier). Partial buffer = Fs, disjoint from Xs.

        // decoder on f32 accumulators: p[j] = sum_ch elu(x2[j+1][ch]) * W_dec[ch]
        float wd[4];
        {
            const float4 w4 = *(const float4*)&W_dec[wave*16 + q*4];
            wd[0] = w4.x; wd[1] = w4.y; wd[2] = w4.z; wd[3] = w4.w;
        }
        float* part = (float*)Fs;   // [8 waves][12 joints][16 graphs] f32 = 6 KB
        #pragma unroll
        for (int j = 0; j < 12; j++) {
            float pp = 0.0f;
            #pragma unroll
            for (int r = 0; r < 4; r++)
                pp += eluf(acc[j+1][r]) * wd[r];
            pp += __shfl_xor(pp, 16);   // sum over q (channel quads)
            pp += __shfl_xor(pp, 32);
            if (q == 0)
                part[wave*192 + j*16 + c] = pp;
        }
        __syncthreads();
        if (tid < 192) {   // t = c2*12 + j2 -> coalesced out stores
            const int c2 = tid / 12, j2 = tid - c2*12;
            float ssum = 0.0f;
            #pragma unroll
            for (int w = 0; w < 8; w++)
                ssum += part[w*192 + j2*16 + c2];
            if ((g0 + c2) < B)
                out[(g0 + c2)*12 + j2] = ssum + b_dec[0];
        }
    }
}

extern "C" void kernel_launch(void* const* d_in, const int* in_sizes, int n_in,
                              void* d_out, int out_size, void* d_ws, size_t ws_size,
                              hipStream_t stream) {
    const float* obs   = (const float*)d_in[0];
    const float* We_b  = (const float*)d_in[1];
    const float* be_b  = (const float*)d_in[2];
    const float* We_j  = (const float*)d_in[3];
    const float* be_j  = (const float*)d_in[4];
    const float* W_rel = (const float*)d_in[5];
    const float* W_root= (const float*)d_in[6];
    const float* b_rel = (const float*)d_in[7];
    const float* W_dec = (const float*)d_in[8];
    const float* b_dec = (const float*)d_in[9];
    float* out = (float*)d_out;
    __bf16* wsb = (__bf16*)d_ws;

    const int B = in_sizes[0] / OBSROW;
    convert_weights<<<(WS_TOT + 255) / 256, 256, 0, stream>>>(W_rel, W_root, We_b, We_j, wsb);
    const int blocks = (B + GPB - 1) / GPB;
    gnn_fused<<<blocks, NT, 0, stream>>>(obs, be_b, be_j, b_rel, W_dec, b_dec,
                                         wsb, out, B);
}